// Round 2
// baseline (335.294 us; speedup 1.0000x reference)
//
#include <hip/hip_runtime.h>

#define BB 16
#define NN 1024
#define ND 32
#define GC1 64
#define GC2 32
#define AUXD 128
#define ZD 16

// ---------------- K1: h1lin = node @ W1 + b1  (rows = B*N, out width 64)
__global__ __launch_bounds__(256) void k1(const float* __restrict__ node,
                                          const float* __restrict__ W1,
                                          const float* __restrict__ b1,
                                          float* __restrict__ h1lin) {
  __shared__ float W1s[ND][GC1];
  __shared__ float b1s[GC1];
  __shared__ float nds[4][ND];
  int t = threadIdx.x;
  for (int i = t; i < ND * GC1; i += 256) W1s[i / GC1][i % GC1] = W1[i];
  if (t < GC1) b1s[t] = b1[t];
  int row0 = blockIdx.x * 4;
  if (t < 4 * ND) nds[t / ND][t % ND] = node[(size_t)row0 * ND + t];
  __syncthreads();
  int r = t >> 6, d = t & 63;
  float acc = b1s[d];
#pragma unroll
  for (int k = 0; k < ND; ++k) acc += nds[r][k] * W1s[k][d];
  h1lin[(size_t)(row0 + r) * GC1 + d] = acc;
}

// ---------------- K2: stream adj_raw (float4, reg-double-buffered);
//                      a = sum(ch1..4); write adj_s; msg1 = a @ h1lin
#define TN1 16
#define TM1 128
__global__ __launch_bounds__(256) void k2(const float* __restrict__ adj_raw,
                                          const float* __restrict__ h1lin,
                                          float* __restrict__ adj_s,
                                          float* __restrict__ msg1,
                                          int store_adj) {
  __shared__ float a_s[TN1][TM1 + 4];
  int t = threadIdx.x;
  int blk = blockIdx.x;            // 1024 blocks: 64 per batch
  int b = blk >> 6;
  int n0 = (blk & 63) * TN1;
  const float* h1b = h1lin + (size_t)b * NN * GC1;
  int x = t & 31;                  // column group: cols 4x..4x+3 within tile
  int rowp = t >> 5;               // 0..7, rows rowp and rowp+8
  int r = t >> 4;                  // 0..15 (compute row)
  int dg = t & 15;                 // compute col group (4 cols)
  const size_t rstride = (size_t)NN * 5;
  const float* rawb = adj_raw + (size_t)(b * NN + n0) * rstride + 20 * x;

  float4 pf[2][5];
  // prologue: prefetch tile 0
#pragma unroll
  for (int p = 0; p < 2; ++p) {
    const float* rp = rawb + (size_t)(rowp + 8 * p) * rstride;
#pragma unroll
    for (int q = 0; q < 5; ++q) pf[p][q] = *(const float4*)(rp + 4 * q);
  }
  float4 acc = make_float4(0.f, 0.f, 0.f, 0.f);

  for (int tile = 0; tile < NN / TM1; ++tile) {
    int m0 = tile * TM1;
    // channel sums from prefetched regs -> LDS (+ adj_s global)
#pragma unroll
    for (int p = 0; p < 2; ++p) {
      int row = rowp + 8 * p;
      float4 s;
      s.x = pf[p][0].y + pf[p][0].z + pf[p][0].w + pf[p][1].x;
      s.y = pf[p][1].z + pf[p][1].w + pf[p][2].x + pf[p][2].y;
      s.z = pf[p][2].w + pf[p][3].x + pf[p][3].y + pf[p][3].z;
      s.w = pf[p][4].x + pf[p][4].y + pf[p][4].z + pf[p][4].w;
      *(float4*)&a_s[row][4 * x] = s;
      if (store_adj)
        *(float4*)&adj_s[(size_t)(b * NN + n0 + row) * NN + m0 + 4 * x] = s;
    }
    __syncthreads();
    // prefetch next tile (overlaps compute phase below)
    if (tile + 1 < NN / TM1) {
      const float* nb = rawb + (size_t)(m0 + TM1) * 5;
#pragma unroll
      for (int p = 0; p < 2; ++p) {
        const float* rp = nb + (size_t)(rowp + 8 * p) * rstride;
#pragma unroll
        for (int q = 0; q < 5; ++q) pf[p][q] = *(const float4*)(rp + 4 * q);
      }
    }
    // msg accumulation: acc += a_s[r][m] * h1[m][dg*4..+3]
#pragma unroll 4
    for (int mm = 0; mm < TM1; mm += 4) {
      float4 av = *(const float4*)&a_s[r][mm];
      const float* hp = h1b + (size_t)(m0 + mm) * GC1 + dg * 4;
      float4 h0 = *(const float4*)(hp);
      float4 h1v = *(const float4*)(hp + GC1);
      float4 h2v = *(const float4*)(hp + 2 * GC1);
      float4 h3v = *(const float4*)(hp + 3 * GC1);
      acc.x += av.x * h0.x + av.y * h1v.x + av.z * h2v.x + av.w * h3v.x;
      acc.y += av.x * h0.y + av.y * h1v.y + av.z * h2v.y + av.w * h3v.y;
      acc.z += av.x * h0.z + av.y * h1v.z + av.z * h2v.z + av.w * h3v.z;
      acc.w += av.x * h0.w + av.y * h1v.w + av.z * h2v.w + av.w * h3v.w;
    }
    __syncthreads();
  }
  *(float4*)(msg1 + (size_t)(b * NN + n0 + r) * GC1 + dg * 4) = acc;
}

// ---------------- K3: h2lin = (msg1 + h1lin) @ W2 + b2
__global__ __launch_bounds__(256) void k3(const float* __restrict__ msg1,
                                          const float* __restrict__ h1lin,
                                          const float* __restrict__ W2,
                                          const float* __restrict__ b2,
                                          float* __restrict__ h2lin) {
  __shared__ float W2s[GC1][GC2];
  __shared__ float b2s[GC2];
  __shared__ float xs[8][GC1];
  int t = threadIdx.x;
  for (int i = t; i < GC1 * GC2; i += 256) W2s[i / GC2][i % GC2] = W2[i];
  if (t < GC2) b2s[t] = b2[t];
  size_t base = (size_t)blockIdx.x * 8 * GC1;
  for (int i = t; i < 8 * GC1; i += 256) xs[i / GC1][i % GC1] = msg1[base + i] + h1lin[base + i];
  __syncthreads();
  int r = t >> 5, dd = t & 31;
  float acc = b2s[dd];
#pragma unroll
  for (int k = 0; k < GC1; ++k) acc += xs[r][k] * W2s[k][dd];
  h2lin[(size_t)(blockIdx.x * 8 + r) * GC2 + dd] = acc;
}

// ---------------- K4: h = adj_s @ h2lin + h2lin   (float4 + reg prefetch)
#define TN2 16
#define TM2 128
template <bool FROM_RAW>
__global__ __launch_bounds__(256) void k4(const float* __restrict__ adj_src,
                                          const float* __restrict__ h2lin,
                                          float* __restrict__ hout) {
  __shared__ float a_s[TN2][TM2 + 4];
  int t = threadIdx.x;
  int blk = blockIdx.x;            // 1024 blocks: 64 per batch
  int b = blk >> 6;
  int n0 = (blk & 63) * TN2;
  const float* h2b = h2lin + (size_t)b * NN * GC2;
  int x = t & 31;
  int rowp = t >> 5;               // 0..7
  int r = t >> 4;                  // 0..15
  int dg = t & 15;                 // cols 2dg..2dg+1
  const size_t rstride5 = (size_t)NN * 5;

  float4 pfr[2][5];
  float4 pfs[2];
  // prologue
#pragma unroll
  for (int p = 0; p < 2; ++p) {
    if (FROM_RAW) {
      const float* rp = adj_src + (size_t)(b * NN + n0 + rowp + 8 * p) * rstride5 + 20 * x;
#pragma unroll
      for (int q = 0; q < 5; ++q) pfr[p][q] = *(const float4*)(rp + 4 * q);
    } else {
      pfs[p] = *(const float4*)&adj_src[(size_t)(b * NN + n0 + rowp + 8 * p) * NN + 4 * x];
    }
  }
  float2 acc = make_float2(0.f, 0.f);

  for (int tile = 0; tile < NN / TM2; ++tile) {
    int m0 = tile * TM2;
#pragma unroll
    for (int p = 0; p < 2; ++p) {
      int row = rowp + 8 * p;
      float4 s;
      if (FROM_RAW) {
        s.x = pfr[p][0].y + pfr[p][0].z + pfr[p][0].w + pfr[p][1].x;
        s.y = pfr[p][1].z + pfr[p][1].w + pfr[p][2].x + pfr[p][2].y;
        s.z = pfr[p][2].w + pfr[p][3].x + pfr[p][3].y + pfr[p][3].z;
        s.w = pfr[p][4].x + pfr[p][4].y + pfr[p][4].z + pfr[p][4].w;
      } else {
        s = pfs[p];
      }
      *(float4*)&a_s[row][4 * x] = s;
    }
    __syncthreads();
    if (tile + 1 < NN / TM2) {
      int m1 = m0 + TM2;
#pragma unroll
      for (int p = 0; p < 2; ++p) {
        if (FROM_RAW) {
          const float* rp = adj_src + (size_t)(b * NN + n0 + rowp + 8 * p) * rstride5 + (size_t)m1 * 5 + 20 * x;
#pragma unroll
          for (int q = 0; q < 5; ++q) pfr[p][q] = *(const float4*)(rp + 4 * q);
        } else {
          pfs[p] = *(const float4*)&adj_src[(size_t)(b * NN + n0 + rowp + 8 * p) * NN + m1 + 4 * x];
        }
      }
    }
#pragma unroll 4
    for (int mm = 0; mm < TM2; mm += 4) {
      float4 av = *(const float4*)&a_s[r][mm];
      const float* hp = h2b + (size_t)(m0 + mm) * GC2 + dg * 2;
      float2 h0 = *(const float2*)(hp);
      float2 h1v = *(const float2*)(hp + GC2);
      float2 h2v = *(const float2*)(hp + 2 * GC2);
      float2 h3v = *(const float2*)(hp + 3 * GC2);
      acc.x += av.x * h0.x + av.y * h1v.x + av.z * h2v.x + av.w * h3v.x;
      acc.y += av.x * h0.y + av.y * h1v.y + av.z * h2v.y + av.w * h3v.y;
    }
    __syncthreads();
  }
  size_t row = (size_t)(b * NN + n0 + r);
  float2 sv = *(const float2*)(h2lin + row * GC2 + dg * 2);
  acc.x += sv.x; acc.y += sv.y;
  *(float2*)(hout + row * GC2 + dg * 2) = acc;
}

// ---------------- K5: gate = sigmoid(x@Ws+bs)*tanh(x@Wt+bt); partial node-sum per block
#define TR 32
__global__ __launch_bounds__(256) void k5(const float* __restrict__ h,
                                          const float* __restrict__ node,
                                          const float* __restrict__ Ws,
                                          const float* __restrict__ bs,
                                          const float* __restrict__ Wt,
                                          const float* __restrict__ bt,
                                          float* __restrict__ partials) {
  __shared__ float xs[TR][GC2 + ND];   // 32 x 64
  __shared__ float red[2][AUXD];
  int t = threadIdx.x;
  int blk = blockIdx.x;                // 512 blocks: 32 per batch
  int b = blk >> 5;
  int n0 = (blk & 31) * TR;
  for (int i = t; i < TR * GC2; i += 256) {
    int rr = i >> 5, kk = i & 31;
    xs[rr][kk] = h[((size_t)(b * NN + n0 + rr)) * GC2 + kk];
  }
  for (int i = t; i < TR * ND; i += 256) {
    int rr = i >> 5, kk = i & 31;
    xs[rr][GC2 + kk] = node[((size_t)(b * NN + n0 + rr)) * ND + kk];
  }
  int c = t & 127;
  int g = t >> 7;
  float wsc[64], wtc[64];
#pragma unroll
  for (int k = 0; k < 64; ++k) {
    wsc[k] = Ws[(size_t)k * AUXD + c];
    wtc[k] = Wt[(size_t)k * AUXD + c];
  }
  float bsv = bs[c], btv = bt[c];
  __syncthreads();
  float part = 0.f;
  for (int rr = g * (TR / 2); rr < (g + 1) * (TR / 2); ++rr) {
    float as_ = bsv, at_ = btv;
#pragma unroll
    for (int k = 0; k < 64; ++k) {
      float xv = xs[rr][k];
      as_ += xv * wsc[k];
      at_ += xv * wtc[k];
    }
    float sg = 1.f / (1.f + __expf(-as_));
    float e2 = __expf(2.f * at_);
    float th = 1.f - 2.f / (e2 + 1.f);
    part += sg * th;
  }
  red[g][c] = part;
  __syncthreads();
  if (t < AUXD) {
    partials[(size_t)blk * AUXD + t] = red[0][t] + red[1][t];
  }
}

// ---------------- K6: reduce partials, tanh, MLP(128->128->128)->head(16)
__global__ __launch_bounds__(128) void k6(const float* __restrict__ partials,
                                          const float* __restrict__ Wm1, const float* __restrict__ bm1,
                                          const float* __restrict__ Wm2, const float* __restrict__ bm2,
                                          const float* __restrict__ Wl, const float* __restrict__ bl,
                                          float* __restrict__ out) {
  __shared__ float g_s[AUXD];
  __shared__ float g2_s[AUXD];
  int t = threadIdx.x;
  int b = blockIdx.x;
  float s = 0.f;
  for (int j = 0; j < 32; ++j) s += partials[((size_t)(b * 32 + j)) * AUXD + t];
  float e2 = __expf(2.f * s);
  g_s[t] = 1.f - 2.f / (e2 + 1.f);
  __syncthreads();
  float acc = bm1[t];
#pragma unroll 16
  for (int k = 0; k < AUXD; ++k) acc += g_s[k] * Wm1[(size_t)k * 128 + t];
  e2 = __expf(2.f * acc);
  g2_s[t] = 1.f - 2.f / (e2 + 1.f);
  __syncthreads();
  acc = bm2[t];
#pragma unroll 16
  for (int k = 0; k < 128; ++k) acc += g2_s[k] * Wm2[(size_t)k * 128 + t];
  e2 = __expf(2.f * acc);
  float g3 = 1.f - 2.f / (e2 + 1.f);
  __syncthreads();
  g_s[t] = g3;
  __syncthreads();
  if (t < ZD) {
    float a = bl[t];
#pragma unroll 16
    for (int k = 0; k < 128; ++k) a += g_s[k] * Wl[(size_t)k * ZD + t];
    out[(size_t)b * ZD + t] = a;
  }
}

extern "C" void kernel_launch(void* const* d_in, const int* in_sizes, int n_in,
                              void* d_out, int out_size, void* d_ws, size_t ws_size,
                              hipStream_t stream) {
  const float* node = (const float*)d_in[0];
  const float* adj_raw = (const float*)d_in[1];
  const float* W1 = (const float*)d_in[2];
  const float* b1 = (const float*)d_in[3];
  const float* W2 = (const float*)d_in[4];
  const float* b2 = (const float*)d_in[5];
  const float* Ws = (const float*)d_in[6];
  const float* bs = (const float*)d_in[7];
  const float* Wt = (const float*)d_in[8];
  const float* bt = (const float*)d_in[9];
  const float* Wm1 = (const float*)d_in[10];
  const float* bm1 = (const float*)d_in[11];
  const float* Wm2 = (const float*)d_in[12];
  const float* bm2 = (const float*)d_in[13];
  const float* Wl = (const float*)d_in[14];
  const float* bl = (const float*)d_in[15];
  float* out = (float*)d_out;
  float* ws = (float*)d_ws;

  size_t o_h1 = 0;
  size_t o_msg1 = o_h1 + (size_t)BB * NN * GC1;
  size_t o_h2 = o_msg1 + (size_t)BB * NN * GC1;
  size_t o_h = o_h2 + (size_t)BB * NN * GC2;
  size_t o_part = o_h + (size_t)BB * NN * GC2;
  size_t o_adj = o_part + (size_t)512 * AUXD;
  size_t need_bytes = (o_adj + (size_t)BB * NN * NN) * sizeof(float);
  bool store = (ws_size >= need_bytes);

  float* h1lin = ws + o_h1;
  float* msg1 = ws + o_msg1;
  float* h2lin = ws + o_h2;
  float* hbuf = ws + o_h;
  float* part = ws + o_part;
  float* adj_s = ws + o_adj;

  k1<<<4096, 256, 0, stream>>>(node, W1, b1, h1lin);
  k2<<<1024, 256, 0, stream>>>(adj_raw, h1lin, adj_s, msg1, store ? 1 : 0);
  k3<<<2048, 256, 0, stream>>>(msg1, h1lin, W2, b2, h2lin);
  if (store) {
    k4<false><<<1024, 256, 0, stream>>>(adj_s, h2lin, hbuf);
  } else {
    k4<true><<<1024, 256, 0, stream>>>(adj_raw, h2lin, hbuf);
  }
  k5<<<512, 256, 0, stream>>>(hbuf, node, Ws, bs, Wt, bt, part);
  k6<<<16, 128, 0, stream>>>(part, Wm1, bm1, Wm2, bm2, Wl, bl, out);
}

// Round 3
// 301.803 us; speedup vs baseline: 1.1110x; 1.1110x over previous
//
#include <hip/hip_runtime.h>

#define BB 16
#define NN 1024
#define ND 32
#define GC1 64
#define GC2 32
#define AUXD 128
#define ZD 16

// ---------------- K1: h1lin = node @ W1 + b1
__global__ __launch_bounds__(256) void k1(const float* __restrict__ node,
                                          const float* __restrict__ W1,
                                          const float* __restrict__ b1,
                                          float* __restrict__ h1lin) {
  __shared__ float W1s[ND][GC1];
  __shared__ float b1s[GC1];
  __shared__ float nds[4][ND];
  int t = threadIdx.x;
  for (int i = t; i < ND * GC1; i += 256) W1s[i / GC1][i % GC1] = W1[i];
  if (t < GC1) b1s[t] = b1[t];
  int row0 = blockIdx.x * 4;
  if (t < 4 * ND) nds[t / ND][t % ND] = node[(size_t)row0 * ND + t];
  __syncthreads();
  int r = t >> 6, d = t & 63;
  float acc = b1s[d];
#pragma unroll
  for (int k = 0; k < ND; ++k) acc += nds[r][k] * W1s[k][d];
  h1lin[(size_t)(row0 + r) * GC1 + d] = acc;
}

// ---------------- K2: stream adj_raw; a = sum(ch1..4); write adj_s;
//                      msg1 = a @ h1lin with h1 TILE STAGED IN LDS
#define TN1 16
#define TM1 128
__global__ __launch_bounds__(256) void k2(const float* __restrict__ adj_raw,
                                          const float* __restrict__ h1lin,
                                          float* __restrict__ adj_s,
                                          float* __restrict__ msg1,
                                          int store_adj) {
  __shared__ float a_s[TN1][TM1 + 4];
  __shared__ float h1s[TM1][GC1];              // 32 KB staged h1 tile
  int t = threadIdx.x;
  int blk = blockIdx.x;                        // 1024 blocks: 64 per batch
  int b = blk >> 6;
  int n0 = (blk & 63) * TN1;
  const float4* h1b4 = (const float4*)(h1lin + (size_t)b * NN * GC1);
  int x = t & 31;                              // adj col group (4 cols)
  int rowp = t >> 5;                           // 0..7 (rows rowp, rowp+8)
  int r = t >> 4;                              // compute row 0..15
  int dg = t & 15;                             // compute col group (4 cols)
  const size_t rs = (size_t)NN * 5;
  float4 acc = make_float4(0.f, 0.f, 0.f, 0.f);

  for (int tile = 0; tile < NN / TM1; ++tile) {
    int m0 = tile * TM1;
    // ---- global loads (regs) ----
    float4 pf[2][5];
#pragma unroll
    for (int p = 0; p < 2; ++p) {
      const float* rp = adj_raw + (size_t)(b * NN + n0 + rowp + 8 * p) * rs + (size_t)(m0 + 4 * x) * 5;
#pragma unroll
      for (int q = 0; q < 5; ++q) pf[p][q] = *(const float4*)(rp + 4 * q);
    }
    float4 hs[8];
#pragma unroll
    for (int q = 0; q < 8; ++q) hs[q] = h1b4[m0 * (GC1 / 4) + q * 256 + t];
    __syncthreads();                           // prev compute done with LDS
    // ---- LDS writes ----
#pragma unroll
    for (int p = 0; p < 2; ++p) {
      int row = rowp + 8 * p;
      float4 s;
      s.x = pf[p][0].y + pf[p][0].z + pf[p][0].w + pf[p][1].x;
      s.y = pf[p][1].z + pf[p][1].w + pf[p][2].x + pf[p][2].y;
      s.z = pf[p][2].w + pf[p][3].x + pf[p][3].y + pf[p][3].z;
      s.w = pf[p][4].x + pf[p][4].y + pf[p][4].z + pf[p][4].w;
      *(float4*)&a_s[row][4 * x] = s;
      if (store_adj)
        *(float4*)&adj_s[(size_t)(b * NN + n0 + row) * NN + m0 + 4 * x] = s;
    }
#pragma unroll
    for (int q = 0; q < 8; ++q) ((float4*)h1s)[q * 256 + t] = hs[q];
    __syncthreads();
    // ---- compute: pure LDS + VALU (no vmcnt deps) ----
#pragma unroll 4
    for (int mm = 0; mm < TM1; mm += 4) {
      float4 av = *(const float4*)&a_s[r][mm];
      const float* hp = &h1s[mm][dg * 4];
      float4 h0 = *(const float4*)(hp);
      float4 h1v = *(const float4*)(hp + GC1);
      float4 h2v = *(const float4*)(hp + 2 * GC1);
      float4 h3v = *(const float4*)(hp + 3 * GC1);
      acc.x += av.x * h0.x + av.y * h1v.x + av.z * h2v.x + av.w * h3v.x;
      acc.y += av.x * h0.y + av.y * h1v.y + av.z * h2v.y + av.w * h3v.y;
      acc.z += av.x * h0.z + av.y * h1v.z + av.z * h2v.z + av.w * h3v.z;
      acc.w += av.x * h0.w + av.y * h1v.w + av.z * h2v.w + av.w * h3v.w;
    }
  }
  *(float4*)(msg1 + (size_t)(b * NN + n0 + r) * GC1 + dg * 4) = acc;
}

// ---------------- K3: h2lin = (msg1 + h1lin) @ W2 + b2
__global__ __launch_bounds__(256) void k3(const float* __restrict__ msg1,
                                          const float* __restrict__ h1lin,
                                          const float* __restrict__ W2,
                                          const float* __restrict__ b2,
                                          float* __restrict__ h2lin) {
  __shared__ float W2s[GC1][GC2];
  __shared__ float b2s[GC2];
  __shared__ float xs[8][GC1];
  int t = threadIdx.x;
  for (int i = t; i < GC1 * GC2; i += 256) W2s[i / GC2][i % GC2] = W2[i];
  if (t < GC2) b2s[t] = b2[t];
  size_t base = (size_t)blockIdx.x * 8 * GC1;
  for (int i = t; i < 8 * GC1; i += 256) xs[i / GC1][i % GC1] = msg1[base + i] + h1lin[base + i];
  __syncthreads();
  int r = t >> 5, dd = t & 31;
  float acc = b2s[dd];
#pragma unroll
  for (int k = 0; k < GC1; ++k) acc += xs[r][k] * W2s[k][dd];
  h2lin[(size_t)(blockIdx.x * 8 + r) * GC2 + dd] = acc;
}

// ---------------- K4: h = adj_s @ h2lin + h2lin, h2 tile staged in LDS
#define TN2 16
#define TM2 128
template <bool FROM_RAW>
__global__ __launch_bounds__(256) void k4(const float* __restrict__ adj_src,
                                          const float* __restrict__ h2lin,
                                          float* __restrict__ hout) {
  __shared__ float a_s[TN2][TM2 + 4];
  __shared__ float h2s[TM2][GC2];              // 16 KB
  int t = threadIdx.x;
  int blk = blockIdx.x;                        // 1024 blocks: 64 per batch
  int b = blk >> 6;
  int n0 = (blk & 63) * TN2;
  const float4* h2b4 = (const float4*)(h2lin + (size_t)b * NN * GC2);
  int r = t >> 4;                              // compute row 0..15
  int cg = (t >> 1) & 7;                       // col group (4 cols)
  int hh = t & 1;                              // m-half
  const size_t rs5 = (size_t)NN * 5;
  float4 acc = make_float4(0.f, 0.f, 0.f, 0.f);

  for (int tile = 0; tile < NN / TM2; ++tile) {
    int m0 = tile * TM2;
    // ---- global loads ----
    float4 af[2];
    float4 pfr[2][5];
    if (FROM_RAW) {
      int x = t & 31, rowp = t >> 5;
#pragma unroll
      for (int p = 0; p < 2; ++p) {
        const float* rp = adj_src + (size_t)(b * NN + n0 + rowp + 8 * p) * rs5 + (size_t)(m0 + 4 * x) * 5;
#pragma unroll
        for (int q = 0; q < 5; ++q) pfr[p][q] = *(const float4*)(rp + 4 * q);
      }
    } else {
#pragma unroll
      for (int p = 0; p < 2; ++p) {
        int idx = p * 256 + t;
        int row = idx >> 5;                    // 0..15
        int col = idx & 31;                    // float4 col
        af[p] = *(const float4*)&adj_src[(size_t)(b * NN + n0 + row) * NN + m0 + col * 4];
      }
    }
    float4 hf[4];
#pragma unroll
    for (int q = 0; q < 4; ++q) hf[q] = h2b4[m0 * (GC2 / 4) + q * 256 + t];
    __syncthreads();
    // ---- LDS writes ----
    if (FROM_RAW) {
      int x = t & 31, rowp = t >> 5;
#pragma unroll
      for (int p = 0; p < 2; ++p) {
        int row = rowp + 8 * p;
        float4 s;
        s.x = pfr[p][0].y + pfr[p][0].z + pfr[p][0].w + pfr[p][1].x;
        s.y = pfr[p][1].z + pfr[p][1].w + pfr[p][2].x + pfr[p][2].y;
        s.z = pfr[p][2].w + pfr[p][3].x + pfr[p][3].y + pfr[p][3].z;
        s.w = pfr[p][4].x + pfr[p][4].y + pfr[p][4].z + pfr[p][4].w;
        *(float4*)&a_s[row][4 * x] = s;
      }
    } else {
#pragma unroll
      for (int p = 0; p < 2; ++p) {
        int idx = p * 256 + t;
        int row = idx >> 5;
        int col = idx & 31;
        *(float4*)&a_s[row][col * 4] = af[p];
      }
    }
#pragma unroll
    for (int q = 0; q < 4; ++q) ((float4*)h2s)[q * 256 + t] = hf[q];
    __syncthreads();
    // ---- compute (m-half per thread) ----
#pragma unroll 4
    for (int mm = 0; mm < TM2 / 2; mm += 4) {
      int m = hh * (TM2 / 2) + mm;
      float4 av = *(const float4*)&a_s[r][m];
      const float* hp = &h2s[m][cg * 4];
      float4 h0 = *(const float4*)(hp);
      float4 h1v = *(const float4*)(hp + GC2);
      float4 h2v = *(const float4*)(hp + 2 * GC2);
      float4 h3v = *(const float4*)(hp + 3 * GC2);
      acc.x += av.x * h0.x + av.y * h1v.x + av.z * h2v.x + av.w * h3v.x;
      acc.y += av.x * h0.y + av.y * h1v.y + av.z * h2v.y + av.w * h3v.y;
      acc.z += av.x * h0.z + av.y * h1v.z + av.z * h2v.z + av.w * h3v.z;
      acc.w += av.x * h0.w + av.y * h1v.w + av.z * h2v.w + av.w * h3v.w;
    }
  }
  // ---- 2-way m-split reduce via LDS, + self term, store ----
  __syncthreads();
  float4* red = (float4*)a_s;                  // [2][16][8] float4 = 4 KB
  red[(hh * TN2 + r) * 8 + cg] = acc;
  __syncthreads();
  if (t < 128) {
    int rr = t >> 3, cc = t & 7;
    float4 s0 = red[(0 * TN2 + rr) * 8 + cc];
    float4 s1 = red[(1 * TN2 + rr) * 8 + cc];
    size_t row = (size_t)(b * NN + n0 + rr);
    float4 sv = *(const float4*)(h2lin + row * GC2 + cc * 4);
    float4 o;
    o.x = s0.x + s1.x + sv.x;
    o.y = s0.y + s1.y + sv.y;
    o.z = s0.z + s1.z + sv.z;
    o.w = s0.w + s1.w + sv.w;
    *(float4*)(hout + row * GC2 + cc * 4) = o;
  }
}

// ---------------- K5: gate = sigmoid(x@Ws+bs)*tanh(x@Wt+bt); partial node-sum
#define TR 32
__global__ __launch_bounds__(256) void k5(const float* __restrict__ h,
                                          const float* __restrict__ node,
                                          const float* __restrict__ Ws,
                                          const float* __restrict__ bs,
                                          const float* __restrict__ Wt,
                                          const float* __restrict__ bt,
                                          float* __restrict__ partials) {
  __shared__ float xs[TR][GC2 + ND];
  __shared__ float red[2][AUXD];
  int t = threadIdx.x;
  int blk = blockIdx.x;                        // 512 blocks: 32 per batch
  int b = blk >> 5;
  int n0 = (blk & 31) * TR;
  for (int i = t; i < TR * GC2; i += 256) {
    int rr = i >> 5, kk = i & 31;
    xs[rr][kk] = h[((size_t)(b * NN + n0 + rr)) * GC2 + kk];
  }
  for (int i = t; i < TR * ND; i += 256) {
    int rr = i >> 5, kk = i & 31;
    xs[rr][GC2 + kk] = node[((size_t)(b * NN + n0 + rr)) * ND + kk];
  }
  int c = t & 127;
  int g = t >> 7;
  float wsc[64], wtc[64];
#pragma unroll
  for (int k = 0; k < 64; ++k) {
    wsc[k] = Ws[(size_t)k * AUXD + c];
    wtc[k] = Wt[(size_t)k * AUXD + c];
  }
  float bsv = bs[c], btv = bt[c];
  __syncthreads();
  float part = 0.f;
  for (int rr = g * (TR / 2); rr < (g + 1) * (TR / 2); ++rr) {
    float as_ = bsv, at_ = btv;
#pragma unroll
    for (int k = 0; k < 64; ++k) {
      float xv = xs[rr][k];
      as_ += xv * wsc[k];
      at_ += xv * wtc[k];
    }
    float sg = 1.f / (1.f + __expf(-as_));
    float e2 = __expf(2.f * at_);
    float th = 1.f - 2.f / (e2 + 1.f);
    part += sg * th;
  }
  red[g][c] = part;
  __syncthreads();
  if (t < AUXD) partials[(size_t)blk * AUXD + t] = red[0][t] + red[1][t];
}

// ---------------- K6: reduce partials, tanh, MLP -> head
__global__ __launch_bounds__(128) void k6(const float* __restrict__ partials,
                                          const float* __restrict__ Wm1, const float* __restrict__ bm1,
                                          const float* __restrict__ Wm2, const float* __restrict__ bm2,
                                          const float* __restrict__ Wl, const float* __restrict__ bl,
                                          float* __restrict__ out) {
  __shared__ float g_s[AUXD];
  __shared__ float g2_s[AUXD];
  int t = threadIdx.x;
  int b = blockIdx.x;
  float s = 0.f;
  for (int j = 0; j < 32; ++j) s += partials[((size_t)(b * 32 + j)) * AUXD + t];
  float e2 = __expf(2.f * s);
  g_s[t] = 1.f - 2.f / (e2 + 1.f);
  __syncthreads();
  float acc = bm1[t];
#pragma unroll 16
  for (int k = 0; k < AUXD; ++k) acc += g_s[k] * Wm1[(size_t)k * 128 + t];
  e2 = __expf(2.f * acc);
  g2_s[t] = 1.f - 2.f / (e2 + 1.f);
  __syncthreads();
  acc = bm2[t];
#pragma unroll 16
  for (int k = 0; k < 128; ++k) acc += g2_s[k] * Wm2[(size_t)k * 128 + t];
  e2 = __expf(2.f * acc);
  float g3 = 1.f - 2.f / (e2 + 1.f);
  __syncthreads();
  g_s[t] = g3;
  __syncthreads();
  if (t < ZD) {
    float a = bl[t];
#pragma unroll 16
    for (int k = 0; k < 128; ++k) a += g_s[k] * Wl[(size_t)k * ZD + t];
    out[(size_t)b * ZD + t] = a;
  }
}

extern "C" void kernel_launch(void* const* d_in, const int* in_sizes, int n_in,
                              void* d_out, int out_size, void* d_ws, size_t ws_size,
                              hipStream_t stream) {
  const float* node = (const float*)d_in[0];
  const float* adj_raw = (const float*)d_in[1];
  const float* W1 = (const float*)d_in[2];
  const float* b1 = (const float*)d_in[3];
  const float* W2 = (const float*)d_in[4];
  const float* b2 = (const float*)d_in[5];
  const float* Ws = (const float*)d_in[6];
  const float* bs = (const float*)d_in[7];
  const float* Wt = (const float*)d_in[8];
  const float* bt = (const float*)d_in[9];
  const float* Wm1 = (const float*)d_in[10];
  const float* bm1 = (const float*)d_in[11];
  const float* Wm2 = (const float*)d_in[12];
  const float* bm2 = (const float*)d_in[13];
  const float* Wl = (const float*)d_in[14];
  const float* bl = (const float*)d_in[15];
  float* out = (float*)d_out;
  float* ws = (float*)d_ws;

  size_t o_h1 = 0;
  size_t o_msg1 = o_h1 + (size_t)BB * NN * GC1;
  size_t o_h2 = o_msg1 + (size_t)BB * NN * GC1;
  size_t o_h = o_h2 + (size_t)BB * NN * GC2;
  size_t o_part = o_h + (size_t)BB * NN * GC2;
  size_t o_adj = o_part + (size_t)512 * AUXD;
  size_t need_bytes = (o_adj + (size_t)BB * NN * NN) * sizeof(float);
  bool store = (ws_size >= need_bytes);

  float* h1lin = ws + o_h1;
  float* msg1 = ws + o_msg1;
  float* h2lin = ws + o_h2;
  float* hbuf = ws + o_h;
  float* part = ws + o_part;
  float* adj_s = ws + o_adj;

  k1<<<4096, 256, 0, stream>>>(node, W1, b1, h1lin);
  k2<<<1024, 256, 0, stream>>>(adj_raw, h1lin, adj_s, msg1, store ? 1 : 0);
  k3<<<2048, 256, 0, stream>>>(msg1, h1lin, W2, b2, h2lin);
  if (store) {
    k4<false><<<1024, 256, 0, stream>>>(adj_s, h2lin, hbuf);
  } else {
    k4<true><<<1024, 256, 0, stream>>>(adj_raw, h2lin, hbuf);
  }
  k5<<<512, 256, 0, stream>>>(hbuf, node, Ws, bs, Wt, bt, part);
  k6<<<16, 128, 0, stream>>>(part, Wm1, bm1, Wm2, bm2, Wl, bl, out);
}

// Round 4
// 190.659 us; speedup vs baseline: 1.7586x; 1.5829x over previous
//
#include <hip/hip_runtime.h>

#define BB 16
#define NN 1024
#define ND 32
#define GC1 64
#define GC2 32
#define AUXD 128
#define ZD 16
#define TN 64

#define FMA4(A, sc, V) {A.x += (sc)*(V).x; A.y += (sc)*(V).y; A.z += (sc)*(V).z; A.w += (sc)*(V).w;}

// ---------------- K1: h1lin = node @ W1 + b1
__global__ __launch_bounds__(256) void k1(const float* __restrict__ node,
                                          const float* __restrict__ W1,
                                          const float* __restrict__ b1,
                                          float* __restrict__ h1lin) {
  __shared__ float W1s[ND][GC1];
  __shared__ float b1s[GC1];
  __shared__ float nds[4][ND];
  int t = threadIdx.x;
  for (int i = t; i < ND * GC1; i += 256) W1s[i / GC1][i % GC1] = W1[i];
  if (t < GC1) b1s[t] = b1[t];
  int row0 = blockIdx.x * 4;
  if (t < 4 * ND) nds[t / ND][t % ND] = node[(size_t)row0 * ND + t];
  __syncthreads();
  int r = t >> 6, d = t & 63;
  float acc = b1s[d];
#pragma unroll
  for (int k = 0; k < ND; ++k) acc += nds[r][k] * W1s[k][d];
  h1lin[(size_t)(row0 + r) * GC1 + d] = acc;
}

// ---------------- K2: stream adj_raw; write adj_s; msgpart[mq] = a_panel @ h1lin
// grid 1024 = b(16) x mq(4) x rowtile(16); per block: 64 rows x 256 m, 8 tiles of 32 m
#define TMK2 32
#define NTK2 8
__global__ __launch_bounds__(256, 4) void k2(const float* __restrict__ adj_raw,
                                             const float* __restrict__ h1lin,
                                             float* __restrict__ adj_s,
                                             float* __restrict__ msgpart,
                                             int store_adj) {
  __shared__ float a_s[TMK2][TN + 4];     // [m][row] transposed
  __shared__ float4 h1s4[TMK2 * 16];      // [m][col] 32x64 floats
  int t = threadIdx.x;
  int blk = blockIdx.x;
  int rt = blk & 15, mq = (blk >> 4) & 3, b = blk >> 6;
  int n0 = rt * TN;
  int mbase = mq * 256;
  const float4* h1b4 = (const float4*)(h1lin + (size_t)b * NN * GC1);
  int arow = t >> 2, aq = t & 3;          // staging: row 0..63, quarter 0..3 (8 elems)
  const float* rawrow = adj_raw + (size_t)(b * NN + n0 + arow) * ((size_t)NN * 5);
  int rg = t >> 4, cg = t & 15;           // compute: rows 4rg.., cols 4cg..

  float4 pf[10];
  float* pfv = (float*)pf;
  float4 hreg[2];
  float4 acc[4];
#pragma unroll
  for (int i = 0; i < 4; ++i) acc[i] = make_float4(0.f, 0.f, 0.f, 0.f);

  // prologue: issue tile 0 loads
  {
    const float4* gp = (const float4*)(rawrow + (size_t)(mbase + aq * 8) * 5);
#pragma unroll
    for (int q = 0; q < 10; ++q) pf[q] = gp[q];
#pragma unroll
    for (int k = 0; k < 2; ++k) hreg[k] = h1b4[mbase * 16 + k * 256 + t];
  }

  for (int tile = 0; tile < NTK2; ++tile) {
    int m0 = mbase + tile * TMK2;
    __syncthreads();                      // prev compute done with LDS
    float s[8];
#pragma unroll
    for (int i = 0; i < 8; ++i) {
      s[i] = pfv[5 * i + 1] + pfv[5 * i + 2] + pfv[5 * i + 3] + pfv[5 * i + 4];
      a_s[aq * 8 + i][arow] = s[i];
    }
#pragma unroll
    for (int k = 0; k < 2; ++k) h1s4[k * 256 + t] = hreg[k];
    __syncthreads();
    // issue next-tile loads + adj_s stores: overlap with compute below
    if (tile + 1 < NTK2) {
      const float4* gp = (const float4*)(rawrow + (size_t)(m0 + TMK2 + aq * 8) * 5);
#pragma unroll
      for (int q = 0; q < 10; ++q) pf[q] = gp[q];
#pragma unroll
      for (int k = 0; k < 2; ++k) hreg[k] = h1b4[(m0 + TMK2) * 16 + k * 256 + t];
    }
    if (store_adj) {
      float* dst = adj_s + (size_t)(b * NN + n0 + arow) * NN + m0 + aq * 8;
      *(float4*)dst = make_float4(s[0], s[1], s[2], s[3]);
      *(float4*)(dst + 4) = make_float4(s[4], s[5], s[6], s[7]);
    }
#pragma unroll
    for (int m = 0; m < TMK2; ++m) {
      float4 av = *(const float4*)&a_s[m][rg * 4];
      float4 hv = h1s4[m * 16 + cg];
      FMA4(acc[0], av.x, hv);
      FMA4(acc[1], av.y, hv);
      FMA4(acc[2], av.z, hv);
      FMA4(acc[3], av.w, hv);
    }
  }
  size_t mpo = (size_t)mq * ((size_t)BB * NN * GC1);
#pragma unroll
  for (int i = 0; i < 4; ++i) {
    *(float4*)(msgpart + mpo + ((size_t)(b * NN) + n0 + rg * 4 + i) * GC1 + cg * 4) = acc[i];
  }
}

// ---------------- K3: h2lin = (sum_q msgpart[q] + h1lin) @ W2 + b2
__global__ __launch_bounds__(256) void k3(const float* __restrict__ msgpart,
                                          const float* __restrict__ h1lin,
                                          const float* __restrict__ W2,
                                          const float* __restrict__ b2,
                                          float* __restrict__ h2lin) {
  __shared__ float W2s[GC1][GC2];
  __shared__ float b2s[GC2];
  __shared__ float xs[8][GC1];
  int t = threadIdx.x;
  for (int i = t; i < GC1 * GC2; i += 256) W2s[i / GC2][i % GC2] = W2[i];
  if (t < GC2) b2s[t] = b2[t];
  size_t base = (size_t)blockIdx.x * 8 * GC1;
  const size_t QS = (size_t)BB * NN * GC1;
  for (int i = t; i < 8 * GC1; i += 256) {
    float v = h1lin[base + i] + msgpart[base + i] + msgpart[QS + base + i]
            + msgpart[2 * QS + base + i] + msgpart[3 * QS + base + i];
    xs[i / GC1][i % GC1] = v;
  }
  __syncthreads();
  int r = t >> 5, dd = t & 31;
  float acc = b2s[dd];
#pragma unroll
  for (int k = 0; k < GC1; ++k) acc += xs[r][k] * W2s[k][dd];
  h2lin[(size_t)(blockIdx.x * 8 + r) * GC2 + dd] = acc;
}

// ---------------- K4: hpart[mq] = adj_s_panel @ h2lin  (self-term added in k5)
// grid 1024 = b(16) x mq(4) x rowtile(16); per block 64 rows x 256 m, 4 tiles of 64 m
#define TMK4 64
#define NTK4 4
__global__ __launch_bounds__(256, 4) void k4(const float* __restrict__ adj_s,
                                             const float* __restrict__ h2lin,
                                             float* __restrict__ hpart) {
  __shared__ float a_s[TMK4][TN + 4];     // [m][row]
  __shared__ float4 h2s4[TMK4 * 8];       // [m][col] 64x32 floats
  int t = threadIdx.x;
  int blk = blockIdx.x;
  int rt = blk & 15, mq = (blk >> 4) & 3, b = blk >> 6;
  int n0 = rt * TN;
  int mbase = mq * 256;
  const float4* a4 = (const float4*)adj_s;
  const float4* h2b4 = (const float4*)(h2lin + (size_t)b * NN * GC2);
  int rg = t >> 4, cg = t & 15;           // compute: rows 4rg.., cols 2cg..

  float4 areg[4];
  float4 hreg[2];
  float2 acc[4];
#pragma unroll
  for (int i = 0; i < 4; ++i) acc[i] = make_float2(0.f, 0.f);

  // prologue
  {
#pragma unroll
    for (int k = 0; k < 4; ++k) {
      int id = k * 256 + t;
      areg[k] = a4[((size_t)(b * NN + n0 + (id >> 4))) * (NN / 4) + (mbase >> 2) + (id & 15)];
    }
#pragma unroll
    for (int k = 0; k < 2; ++k) hreg[k] = h2b4[mbase * 8 + k * 256 + t];
  }

  for (int tile = 0; tile < NTK4; ++tile) {
    int m0 = mbase + tile * TMK4;
    __syncthreads();
#pragma unroll
    for (int k = 0; k < 4; ++k) {
      int id = k * 256 + t;
      int row = id >> 4, c4 = id & 15;
      a_s[4 * c4 + 0][row] = areg[k].x;
      a_s[4 * c4 + 1][row] = areg[k].y;
      a_s[4 * c4 + 2][row] = areg[k].z;
      a_s[4 * c4 + 3][row] = areg[k].w;
    }
#pragma unroll
    for (int k = 0; k < 2; ++k) h2s4[k * 256 + t] = hreg[k];
    __syncthreads();
    if (tile + 1 < NTK4) {
      int m1 = m0 + TMK4;
#pragma unroll
      for (int k = 0; k < 4; ++k) {
        int id = k * 256 + t;
        areg[k] = a4[((size_t)(b * NN + n0 + (id >> 4))) * (NN / 4) + (m1 >> 2) + (id & 15)];
      }
#pragma unroll
      for (int k = 0; k < 2; ++k) hreg[k] = h2b4[m1 * 8 + k * 256 + t];
    }
#pragma unroll
    for (int m = 0; m < TMK4; ++m) {
      float4 av = *(const float4*)&a_s[m][rg * 4];
      float2 hv = ((const float2*)h2s4)[m * 16 + cg];
      acc[0].x += av.x * hv.x; acc[0].y += av.x * hv.y;
      acc[1].x += av.y * hv.x; acc[1].y += av.y * hv.y;
      acc[2].x += av.z * hv.x; acc[2].y += av.z * hv.y;
      acc[3].x += av.w * hv.x; acc[3].y += av.w * hv.y;
    }
  }
  size_t hpo = (size_t)mq * ((size_t)BB * NN * GC2);
#pragma unroll
  for (int i = 0; i < 4; ++i) {
    *(float2*)(hpart + hpo + ((size_t)(b * NN) + n0 + rg * 4 + i) * GC2 + cg * 2) = acc[i];
  }
}

// ---------------- K4_raw fallback (ws too small): h = adj(raw) @ h2 + h2 -> hpart[0]
#define TN2 16
#define TM2 128
__global__ __launch_bounds__(256) void k4_raw(const float* __restrict__ adj_src,
                                              const float* __restrict__ h2lin,
                                              float* __restrict__ hout) {
  __shared__ float a_s[TN2][TM2 + 4];
  __shared__ float h2s[TM2][GC2];
  int t = threadIdx.x;
  int blk = blockIdx.x;
  int b = blk >> 6;
  int n0 = (blk & 63) * TN2;
  const float4* h2b4 = (const float4*)(h2lin + (size_t)b * NN * GC2);
  int r = t >> 4;
  int cg = (t >> 1) & 7;
  int hh = t & 1;
  const size_t rs5 = (size_t)NN * 5;
  float4 acc = make_float4(0.f, 0.f, 0.f, 0.f);

  for (int tile = 0; tile < NN / TM2; ++tile) {
    int m0 = tile * TM2;
    float4 pfr[2][5];
    int x = t & 31, rowp = t >> 5;
#pragma unroll
    for (int p = 0; p < 2; ++p) {
      const float* rp = adj_src + (size_t)(b * NN + n0 + rowp + 8 * p) * rs5 + (size_t)(m0 + 4 * x) * 5;
#pragma unroll
      for (int q = 0; q < 5; ++q) pfr[p][q] = *(const float4*)(rp + 4 * q);
    }
    float4 hf[4];
#pragma unroll
    for (int q = 0; q < 4; ++q) hf[q] = h2b4[m0 * (GC2 / 4) + q * 256 + t];
    __syncthreads();
#pragma unroll
    for (int p = 0; p < 2; ++p) {
      int row = rowp + 8 * p;
      float4 s;
      s.x = pfr[p][0].y + pfr[p][0].z + pfr[p][0].w + pfr[p][1].x;
      s.y = pfr[p][1].z + pfr[p][1].w + pfr[p][2].x + pfr[p][2].y;
      s.z = pfr[p][2].w + pfr[p][3].x + pfr[p][3].y + pfr[p][3].z;
      s.w = pfr[p][4].x + pfr[p][4].y + pfr[p][4].z + pfr[p][4].w;
      *(float4*)&a_s[row][4 * x] = s;
    }
#pragma unroll
    for (int q = 0; q < 4; ++q) ((float4*)h2s)[q * 256 + t] = hf[q];
    __syncthreads();
#pragma unroll 4
    for (int mm = 0; mm < TM2 / 2; mm += 4) {
      int m = hh * (TM2 / 2) + mm;
      float4 av = *(const float4*)&a_s[r][m];
      const float* hp = &h2s[m][cg * 4];
      float4 h0 = *(const float4*)(hp);
      float4 h1v = *(const float4*)(hp + GC2);
      float4 h2v = *(const float4*)(hp + 2 * GC2);
      float4 h3v = *(const float4*)(hp + 3 * GC2);
      acc.x += av.x * h0.x + av.y * h1v.x + av.z * h2v.x + av.w * h3v.x;
      acc.y += av.x * h0.y + av.y * h1v.y + av.z * h2v.y + av.w * h3v.y;
      acc.z += av.x * h0.z + av.y * h1v.z + av.z * h2v.z + av.w * h3v.z;
      acc.w += av.x * h0.w + av.y * h1v.w + av.z * h2v.w + av.w * h3v.w;
    }
    __syncthreads();
  }
  float4* red = (float4*)a_s;
  red[(hh * TN2 + r) * 8 + cg] = acc;
  __syncthreads();
  if (t < 128) {
    int rr = t >> 3, cc = t & 7;
    float4 s0 = red[(0 * TN2 + rr) * 8 + cc];
    float4 s1 = red[(1 * TN2 + rr) * 8 + cc];
    size_t row = (size_t)(b * NN + n0 + rr);
    float4 sv = *(const float4*)(h2lin + row * GC2 + cc * 4);
    float4 o;
    o.x = s0.x + s1.x + sv.x;
    o.y = s0.y + s1.y + sv.y;
    o.z = s0.z + s1.z + sv.z;
    o.w = s0.w + s1.w + sv.w;
    *(float4*)(hout + row * GC2 + cc * 4) = o;
  }
}

// ---------------- K5: gated sum over nodes; reads np h-partials (+h2lin self)
#define TR 32
__global__ __launch_bounds__(256) void k5(const float* __restrict__ hpart,
                                          const float* __restrict__ h2lin,
                                          const float* __restrict__ node,
                                          const float* __restrict__ Ws,
                                          const float* __restrict__ bs,
                                          const float* __restrict__ Wt,
                                          const float* __restrict__ bt,
                                          float* __restrict__ partials,
                                          int np, int addself) {
  __shared__ float xs[TR][GC2 + ND];
  __shared__ float red[2][AUXD];
  int t = threadIdx.x;
  int blk = blockIdx.x;
  int b = blk >> 5;
  int n0 = (blk & 31) * TR;
  const size_t QS2 = (size_t)BB * NN * GC2;
  for (int i = t; i < TR * GC2; i += 256) {
    int rr = i >> 5, kk = i & 31;
    size_t idx = ((size_t)(b * NN + n0 + rr)) * GC2 + kk;
    float v = addself ? h2lin[idx] : 0.f;
    for (int q = 0; q < np; ++q) v += hpart[q * QS2 + idx];
    xs[rr][kk] = v;
  }
  for (int i = t; i < TR * ND; i += 256) {
    int rr = i >> 5, kk = i & 31;
    xs[rr][GC2 + kk] = node[((size_t)(b * NN + n0 + rr)) * ND + kk];
  }
  int c = t & 127;
  int g = t >> 7;
  float wsc[64], wtc[64];
#pragma unroll
  for (int k = 0; k < 64; ++k) {
    wsc[k] = Ws[(size_t)k * AUXD + c];
    wtc[k] = Wt[(size_t)k * AUXD + c];
  }
  float bsv = bs[c], btv = bt[c];
  __syncthreads();
  float part = 0.f;
  for (int rr = g * (TR / 2); rr < (g + 1) * (TR / 2); ++rr) {
    float as_ = bsv, at_ = btv;
#pragma unroll
    for (int k = 0; k < 64; ++k) {
      float xv = xs[rr][k];
      as_ += xv * wsc[k];
      at_ += xv * wtc[k];
    }
    float sg = 1.f / (1.f + __expf(-as_));
    float e2 = __expf(2.f * at_);
    float th = 1.f - 2.f / (e2 + 1.f);
    part += sg * th;
  }
  red[g][c] = part;
  __syncthreads();
  if (t < AUXD) partials[(size_t)blk * AUXD + t] = red[0][t] + red[1][t];
}

// ---------------- K6: reduce partials, tanh, MLP -> head
__global__ __launch_bounds__(128) void k6(const float* __restrict__ partials,
                                          const float* __restrict__ Wm1, const float* __restrict__ bm1,
                                          const float* __restrict__ Wm2, const float* __restrict__ bm2,
                                          const float* __restrict__ Wl, const float* __restrict__ bl,
                                          float* __restrict__ out) {
  __shared__ float g_s[AUXD];
  __shared__ float g2_s[AUXD];
  int t = threadIdx.x;
  int b = blockIdx.x;
  float s = 0.f;
  for (int j = 0; j < 32; ++j) s += partials[((size_t)(b * 32 + j)) * AUXD + t];
  float e2 = __expf(2.f * s);
  g_s[t] = 1.f - 2.f / (e2 + 1.f);
  __syncthreads();
  float acc = bm1[t];
#pragma unroll 16
  for (int k = 0; k < AUXD; ++k) acc += g_s[k] * Wm1[(size_t)k * 128 + t];
  e2 = __expf(2.f * acc);
  g2_s[t] = 1.f - 2.f / (e2 + 1.f);
  __syncthreads();
  acc = bm2[t];
#pragma unroll 16
  for (int k = 0; k < 128; ++k) acc += g2_s[k] * Wm2[(size_t)k * 128 + t];
  e2 = __expf(2.f * acc);
  float g3 = 1.f - 2.f / (e2 + 1.f);
  __syncthreads();
  g_s[t] = g3;
  __syncthreads();
  if (t < ZD) {
    float a = bl[t];
#pragma unroll 16
    for (int k = 0; k < 128; ++k) a += g_s[k] * Wl[(size_t)k * ZD + t];
    out[(size_t)b * ZD + t] = a;
  }
}

extern "C" void kernel_launch(void* const* d_in, const int* in_sizes, int n_in,
                              void* d_out, int out_size, void* d_ws, size_t ws_size,
                              hipStream_t stream) {
  const float* node = (const float*)d_in[0];
  const float* adj_raw = (const float*)d_in[1];
  const float* W1 = (const float*)d_in[2];
  const float* b1 = (const float*)d_in[3];
  const float* W2 = (const float*)d_in[4];
  const float* b2 = (const float*)d_in[5];
  const float* Ws = (const float*)d_in[6];
  const float* bs = (const float*)d_in[7];
  const float* Wt = (const float*)d_in[8];
  const float* bt = (const float*)d_in[9];
  const float* Wm1 = (const float*)d_in[10];
  const float* bm1 = (const float*)d_in[11];
  const float* Wm2 = (const float*)d_in[12];
  const float* bm2 = (const float*)d_in[13];
  const float* Wl = (const float*)d_in[14];
  const float* bl = (const float*)d_in[15];
  float* out = (float*)d_out;
  float* ws = (float*)d_ws;

  size_t o_h1 = 0;                                        // 1,048,576
  size_t o_msgp = o_h1 + (size_t)BB * NN * GC1;           // 4x h1 size
  size_t o_h2 = o_msgp + 4 * (size_t)BB * NN * GC1;       // 524,288
  size_t o_hp = o_h2 + (size_t)BB * NN * GC2;             // 4x
  size_t o_part = o_hp + 4 * (size_t)BB * NN * GC2;       // 65,536
  size_t o_adj = o_part + (size_t)512 * AUXD;
  size_t need_bytes = (o_adj + (size_t)BB * NN * NN) * sizeof(float);
  bool store = (ws_size >= need_bytes);

  float* h1lin = ws + o_h1;
  float* msgpart = ws + o_msgp;
  float* h2lin = ws + o_h2;
  float* hpart = ws + o_hp;
  float* part = ws + o_part;
  float* adj_s = ws + o_adj;

  k1<<<4096, 256, 0, stream>>>(node, W1, b1, h1lin);
  k2<<<1024, 256, 0, stream>>>(adj_raw, h1lin, adj_s, msgpart, store ? 1 : 0);
  k3<<<2048, 256, 0, stream>>>(msgpart, h1lin, W2, b2, h2lin);
  if (store) {
    k4<<<1024, 256, 0, stream>>>(adj_s, h2lin, hpart);
    k5<<<512, 256, 0, stream>>>(hpart, h2lin, node, Ws, bs, Wt, bt, part, 4, 1);
  } else {
    k4_raw<<<1024, 256, 0, stream>>>(adj_raw, h2lin, hpart);
    k5<<<512, 256, 0, stream>>>(hpart, h2lin, node, Ws, bs, Wt, bt, part, 1, 0);
  }
  k6<<<16, 128, 0, stream>>>(part, Wm1, bm1, Wm2, bm2, Wl, bl, out);
}